// Round 1
// baseline (618.783 us; speedup 1.0000x reference)
//
#include <hip/hip_runtime.h>
#include <math.h>

#define BB 64
#define RR 36
#define WW 50
#define DD 1024
#define EPSF 1e-8f

// ws layout (floats): invI[BB*RR]=2304 | invC[BB*WW]=3200 | G[BB*WW*WW]=160000
// total 662 KB

__device__ __forceinline__ void fma4(float& acc, const float4 a, const float4 b) {
    acc = fmaf(a.x, b.x, acc);
    acc = fmaf(a.y, b.y, acc);
    acc = fmaf(a.z, b.z, acc);
    acc = fmaf(a.w, b.w, acc);
}

// One block per row (2304 img rows then 3200 cap rows): inv = 1/(||x||+eps)
__global__ __launch_bounds__(256) void norm_kernel(
        const float* __restrict__ imgs, const float* __restrict__ caps,
        float* __restrict__ invI, float* __restrict__ invC) {
    int row = blockIdx.x;
    const float* src;
    float* dst;
    if (row < BB * RR) { src = imgs + (size_t)row * DD; dst = invI + row; }
    else { int q = row - BB * RR; src = caps + (size_t)q * DD; dst = invC + q; }
    int tid = threadIdx.x;
    float4 v = ((const float4*)src)[tid];   // 256 threads * 4 = 1024 exactly
    float ss = v.x * v.x + v.y * v.y + v.z * v.z + v.w * v.w;
    #pragma unroll
    for (int off = 32; off > 0; off >>= 1) ss += __shfl_down(ss, off, 64);
    __shared__ float part[4];
    if ((tid & 63) == 0) part[tid >> 6] = ss;
    __syncthreads();
    if (tid == 0) {
        float t = part[0] + part[1] + part[2] + part[3];
        *dst = 1.0f / (sqrtf(t) + EPSF);
    }
}

// One block per caption c: G_c = caps[c] @ caps[c]^T  (50x50, raw dots)
__global__ __launch_bounds__(256) void gram_kernel(
        const float* __restrict__ caps, float* __restrict__ G) {
    int c = blockIdx.x;
    const float* cap = caps + (size_t)c * WW * DD;
    __shared__ float cs[64][68];   // rows padded 50->64 (zeros), stride 68 (bank shift)
    int tid = threadIdx.x;
    int tr = tid & 15, tw = tid >> 4;
    float acc[4][4];
    #pragma unroll
    for (int a = 0; a < 4; a++)
        #pragma unroll
        for (int b = 0; b < 4; b++) acc[a][b] = 0.f;

    for (int d0 = 0; d0 < DD; d0 += 64) {
        __syncthreads();
        for (int t = tid; t < 64 * 16; t += 256) {
            int rw = t >> 4, c4 = t & 15;
            float4 v = make_float4(0.f, 0.f, 0.f, 0.f);
            if (rw < WW) v = *(const float4*)(cap + (size_t)rw * DD + d0 + c4 * 4);
            *(float4*)&cs[rw][c4 * 4] = v;
        }
        __syncthreads();
        #pragma unroll 4
        for (int k4 = 0; k4 < 16; k4++) {
            float4 a0 = *(const float4*)&cs[tr][k4 * 4];
            float4 a1 = *(const float4*)&cs[tr + 16][k4 * 4];
            float4 a2 = *(const float4*)&cs[tr + 32][k4 * 4];
            float4 a3 = *(const float4*)&cs[tr + 48][k4 * 4];
            float4 b0 = *(const float4*)&cs[tw][k4 * 4];
            float4 b1 = *(const float4*)&cs[tw + 16][k4 * 4];
            float4 b2 = *(const float4*)&cs[tw + 32][k4 * 4];
            float4 b3 = *(const float4*)&cs[tw + 48][k4 * 4];
            fma4(acc[0][0], a0, b0); fma4(acc[0][1], a0, b1);
            fma4(acc[0][2], a0, b2); fma4(acc[0][3], a0, b3);
            fma4(acc[1][0], a1, b0); fma4(acc[1][1], a1, b1);
            fma4(acc[1][2], a1, b2); fma4(acc[1][3], a1, b3);
            fma4(acc[2][0], a2, b0); fma4(acc[2][1], a2, b1);
            fma4(acc[2][2], a2, b2); fma4(acc[2][3], a2, b3);
            fma4(acc[3][0], a3, b0); fma4(acc[3][1], a3, b1);
            fma4(acc[3][2], a3, b2); fma4(acc[3][3], a3, b3);
        }
    }
    #pragma unroll
    for (int j = 0; j < 4; j++) {
        int wp = tr + 16 * j;
        if (wp >= WW) continue;
        #pragma unroll
        for (int l = 0; l < 4; l++) {
            int w = tw + 16 * l;
            if (w < WW) G[(size_t)c * WW * WW + wp * WW + w] = acc[j][l];
        }
    }
}

// One block per (i,c) pair. Phase 1: T[36][50] = imgs_i @ caps_c^T (raw dots).
// Phase 2a: per-row masked softmax/argmax/mix -> M[36][50], num.
// Phase 2b: den^2 = diag(M G M^T) via small LDS matmul; write out.
__global__ __launch_bounds__(256) void amc_main_kernel(
        const float* __restrict__ imgs, const float* __restrict__ caps,
        const int* __restrict__ img_lens, const int* __restrict__ cap_lens,
        const float* __restrict__ alpha,
        const float* __restrict__ invI, const float* __restrict__ invC,
        const float* __restrict__ G, float* __restrict__ out) {
    int c = blockIdx.x, i = blockIdx.y;
    __shared__ float imgsS[48][36];   // BK=32 cols + 4 pad; rows padded 36->48 (zeros)
    __shared__ float capsS[64][36];   // rows padded 50->64 (zeros)
    __shared__ float Tsh[36][52];
    __shared__ float Msh[48][52];     // rows 36..47 zeroed; cols 50,51 zeroed
    __shared__ float Gsh[64][52];     // rows 50..63 zeroed; cols 50,51 zeroed
    __shared__ float part[16][48];

    int tid = threadIdx.x;
    int tr = tid & 15, tw = tid >> 4;
    float acc[3][4];
    #pragma unroll
    for (int j = 0; j < 3; j++)
        #pragma unroll
        for (int l = 0; l < 4; l++) acc[j][l] = 0.f;

    const float* imgBase = imgs + (size_t)i * RR * DD;
    const float* capBase = caps + (size_t)c * WW * DD;

    for (int d0 = 0; d0 < DD; d0 += 32) {
        __syncthreads();
        {   // imgsS: 48 rows x 8 float4 = 384 items
            int t = tid;
            int rw = t >> 3, c4 = t & 7;
            float4 v = make_float4(0.f, 0.f, 0.f, 0.f);
            if (rw < RR) v = *(const float4*)(imgBase + (size_t)rw * DD + d0 + c4 * 4);
            *(float4*)&imgsS[rw][c4 * 4] = v;
            if (tid < 128) {
                t = tid + 256; rw = t >> 3; c4 = t & 7;
                v = make_float4(0.f, 0.f, 0.f, 0.f);
                if (rw < RR) v = *(const float4*)(imgBase + (size_t)rw * DD + d0 + c4 * 4);
                *(float4*)&imgsS[rw][c4 * 4] = v;
            }
        }
        {   // capsS: 64 rows x 8 float4 = 512 items
            int t = tid;
            int rw = t >> 3, c4 = t & 7;
            float4 v = make_float4(0.f, 0.f, 0.f, 0.f);
            if (rw < WW) v = *(const float4*)(capBase + (size_t)rw * DD + d0 + c4 * 4);
            *(float4*)&capsS[rw][c4 * 4] = v;
            t = tid + 256; rw = t >> 3; c4 = t & 7;
            v = make_float4(0.f, 0.f, 0.f, 0.f);
            if (rw < WW) v = *(const float4*)(capBase + (size_t)rw * DD + d0 + c4 * 4);
            *(float4*)&capsS[rw][c4 * 4] = v;
        }
        __syncthreads();
        #pragma unroll
        for (int k4 = 0; k4 < 8; k4++) {
            float4 a0 = *(const float4*)&imgsS[tr][k4 * 4];
            float4 a1 = *(const float4*)&imgsS[tr + 16][k4 * 4];
            float4 a2 = *(const float4*)&imgsS[tr + 32][k4 * 4];
            float4 b0 = *(const float4*)&capsS[tw][k4 * 4];
            float4 b1 = *(const float4*)&capsS[tw + 16][k4 * 4];
            float4 b2 = *(const float4*)&capsS[tw + 32][k4 * 4];
            float4 b3 = *(const float4*)&capsS[tw + 48][k4 * 4];
            fma4(acc[0][0], a0, b0); fma4(acc[0][1], a0, b1);
            fma4(acc[0][2], a0, b2); fma4(acc[0][3], a0, b3);
            fma4(acc[1][0], a1, b0); fma4(acc[1][1], a1, b1);
            fma4(acc[1][2], a1, b2); fma4(acc[1][3], a1, b3);
            fma4(acc[2][0], a2, b0); fma4(acc[2][1], a2, b1);
            fma4(acc[2][2], a2, b2); fma4(acc[2][3], a2, b3);
        }
    }
    // store T tile
    #pragma unroll
    for (int j = 0; j < 3; j++) {
        int r = tr + 16 * j;
        if (r < RR) {
            #pragma unroll
            for (int l = 0; l < 4; l++) {
                int w = tw + 16 * l;
                if (w < WW) Tsh[r][w] = acc[j][l];
            }
        }
    }
    __syncthreads();

    // Phase 2a: wave 0 (tid<36) does softmax/argmax/mix; tid 36..47 zero Msh pad
    // rows; waves 1..3 fill Gsh concurrently.
    float num = 0.f;
    bool validr = false;
    if (tid < RR) {
        int r = tid;
        int li = img_lens[i];
        int lc = cap_lens[c];
        validr = (r < li);
        float a_mix = 1.0f / (1.0f + expf(-alpha[0]));   // sigmoid
        float one_minus_a = 1.0f - a_mix;
        float inv_ir = invI[i * RR + r];
        // pass 1: max + first-index argmax over valid words (masked = -1 < any cos)
        float maxS = -2.0f;
        int amax = 0;
        for (int w = 0; w < lc; w++) {
            float S = Tsh[r][w] * inv_ir * invC[c * WW + w];
            if (S > maxS) { maxS = S; amax = w; }
        }
        // pass 2: softmax denominator (temperature 0.1 => *10)
        float ssum = 0.f;
        for (int w = 0; w < lc; w++) {
            float S = Tsh[r][w] * inv_ir * invC[c * WW + w];
            ssum += expf((S - maxS) * 10.0f);
        }
        float soft_scale = a_mix / ssum;
        // pass 3: mixed weights -> Msh; num = sum_w m_w * T_w
        for (int w = 0; w < 52; w++) {
            float m = 0.f;
            if (w < lc) {
                float S = Tsh[r][w] * inv_ir * invC[c * WW + w];
                m = expf((S - maxS) * 10.0f) * soft_scale;
                if (w == amax) m += one_minus_a;
                num = fmaf(m, Tsh[r][w], num);
            }
            Msh[r][w] = m;
        }
    } else if (tid < 48) {
        #pragma unroll
        for (int w = 0; w < 52; w++) Msh[tid][w] = 0.f;
    } else if (tid >= 64) {
        const float* Gc = G + (size_t)c * WW * WW;
        for (int t = tid - 64; t < 64 * 52; t += 192) {
            int rw = t / 52, cc = t - rw * 52;
            Gsh[rw][cc] = (rw < WW && cc < WW) ? Gc[rw * WW + cc] : 0.f;
        }
    }
    __syncthreads();

    // Phase 2b: H[r][w] = sum_w' M[r][w'] * G[w][w']  (G symmetric),
    // den2[r] = sum_w M[r][w] * H[r][w]
    float h[3][4];
    #pragma unroll
    for (int j = 0; j < 3; j++)
        #pragma unroll
        for (int l = 0; l < 4; l++) h[j][l] = 0.f;
    #pragma unroll
    for (int k4 = 0; k4 < 13; k4++) {
        float4 m0 = *(const float4*)&Msh[tr][k4 * 4];
        float4 m1 = *(const float4*)&Msh[tr + 16][k4 * 4];
        float4 m2 = *(const float4*)&Msh[tr + 32][k4 * 4];
        float4 g0 = *(const float4*)&Gsh[tw][k4 * 4];
        float4 g1 = *(const float4*)&Gsh[tw + 16][k4 * 4];
        float4 g2 = *(const float4*)&Gsh[tw + 32][k4 * 4];
        float4 g3 = *(const float4*)&Gsh[tw + 48][k4 * 4];
        fma4(h[0][0], m0, g0); fma4(h[0][1], m0, g1);
        fma4(h[0][2], m0, g2); fma4(h[0][3], m0, g3);
        fma4(h[1][0], m1, g0); fma4(h[1][1], m1, g1);
        fma4(h[1][2], m1, g2); fma4(h[1][3], m1, g3);
        fma4(h[2][0], m2, g0); fma4(h[2][1], m2, g1);
        fma4(h[2][2], m2, g2); fma4(h[2][3], m2, g3);
    }
    #pragma unroll
    for (int j = 0; j < 3; j++) {
        int r = tr + 16 * j;
        float p = 0.f;
        #pragma unroll
        for (int l = 0; l < 4; l++) p = fmaf(Msh[r][tw + 16 * l], h[j][l], p);
        part[tw][r] = p;
    }
    __syncthreads();
    if (tid < RR) {
        float den2 = 0.f;
        #pragma unroll
        for (int q = 0; q < 16; q++) den2 += part[q][tid];
        float res = validr ? (num / (sqrtf(den2) + EPSF)) : -1.0f;
        out[((size_t)i * BB + c) * RR + tid] = res;
    }
}

extern "C" void kernel_launch(void* const* d_in, const int* in_sizes, int n_in,
                              void* d_out, int out_size, void* d_ws, size_t ws_size,
                              hipStream_t stream) {
    const float* imgs = (const float*)d_in[0];
    const float* caps = (const float*)d_in[1];
    const int* img_lens = (const int*)d_in[2];
    const int* cap_lens = (const int*)d_in[3];
    const float* alpha = (const float*)d_in[4];
    float* out = (float*)d_out;

    float* ws = (float*)d_ws;
    float* invI = ws;                        // 2304 floats
    float* invC = ws + BB * RR;              // 3200 floats
    float* G = ws + BB * RR + BB * WW;       // 160000 floats

    norm_kernel<<<BB * RR + BB * WW, 256, 0, stream>>>(imgs, caps, invI, invC);
    gram_kernel<<<BB, 256, 0, stream>>>(caps, G);
    amc_main_kernel<<<dim3(BB, BB), 256, 0, stream>>>(
        imgs, caps, img_lens, cap_lens, alpha, invI, invC, G, out);
}

// Round 2
// 375.910 us; speedup vs baseline: 1.6461x; 1.6461x over previous
//
#include <hip/hip_runtime.h>
#include <math.h>

#define BB 64
#define RR 36
#define WW 50
#define DD 1024
#define EPSF 1e-8f

#define GM 2304   // 64*36
#define GN 3200   // 64*50
#define GK 1024

// ws layout (floats): invI[2304] @0 | invC[3200] @2304 | G[160000] @5504 |
// T[7372800] @165504  -> total ~30.2 MB

__device__ __forceinline__ void fma4(float& acc, const float4 a, const float4 b) {
    acc = fmaf(a.x, b.x, acc);
    acc = fmaf(a.y, b.y, acc);
    acc = fmaf(a.z, b.z, acc);
    acc = fmaf(a.w, b.w, acc);
}

// wave-per-row inverse norms: 5504 rows, 4 rows/block
__global__ __launch_bounds__(256) void norm_kernel(
        const float* __restrict__ imgs, const float* __restrict__ caps,
        float* __restrict__ invI, float* __restrict__ invC) {
    int lane = threadIdx.x & 63, wv = threadIdx.x >> 6;
    int row = blockIdx.x * 4 + wv;
    const float* src;
    float* dst;
    if (row < BB * RR) { src = imgs + (size_t)row * DD; dst = invI + row; }
    else { int q = row - BB * RR; src = caps + (size_t)q * DD; dst = invC + q; }
    float ss = 0.f;
    #pragma unroll
    for (int j = 0; j < 4; j++) {
        float4 v = ((const float4*)src)[lane + 64 * j];
        ss += v.x * v.x + v.y * v.y + v.z * v.z + v.w * v.w;
    }
    #pragma unroll
    for (int off = 32; off > 0; off >>= 1) ss += __shfl_down(ss, off, 64);
    if (lane == 0) *dst = 1.0f / (sqrtf(ss) + EPSF);
}

// Gram: grid (c=64, kq=4); each block does K-range [kq*256, kq*256+256),
// atomicAdd into G (zeroed by memset in kernel_launch).
__global__ __launch_bounds__(256) void gram_kernel(
        const float* __restrict__ caps, float* __restrict__ G) {
    int c = blockIdx.x, kq = blockIdx.y;
    const float* cap = caps + (size_t)c * WW * DD + kq * 256;
    __shared__ __align__(16) float cs[64][68];
    int tid = threadIdx.x;
    int tr = tid & 15, tw = tid >> 4;
    float acc[4][4];
    #pragma unroll
    for (int a = 0; a < 4; a++)
        #pragma unroll
        for (int b = 0; b < 4; b++) acc[a][b] = 0.f;

    for (int d0 = 0; d0 < 256; d0 += 64) {
        __syncthreads();
        for (int t = tid; t < 64 * 16; t += 256) {
            int rw = t >> 4, c4 = t & 15;
            float4 v = make_float4(0.f, 0.f, 0.f, 0.f);
            if (rw < WW) v = *(const float4*)(cap + (size_t)rw * DD + d0 + c4 * 4);
            *(float4*)&cs[rw][c4 * 4] = v;
        }
        __syncthreads();
        #pragma unroll 4
        for (int k4 = 0; k4 < 16; k4++) {
            float4 a0 = *(const float4*)&cs[tr][k4 * 4];
            float4 a1 = *(const float4*)&cs[tr + 16][k4 * 4];
            float4 a2 = *(const float4*)&cs[tr + 32][k4 * 4];
            float4 a3 = *(const float4*)&cs[tr + 48][k4 * 4];
            float4 b0 = *(const float4*)&cs[tw][k4 * 4];
            float4 b1 = *(const float4*)&cs[tw + 16][k4 * 4];
            float4 b2 = *(const float4*)&cs[tw + 32][k4 * 4];
            float4 b3 = *(const float4*)&cs[tw + 48][k4 * 4];
            fma4(acc[0][0], a0, b0); fma4(acc[0][1], a0, b1);
            fma4(acc[0][2], a0, b2); fma4(acc[0][3], a0, b3);
            fma4(acc[1][0], a1, b0); fma4(acc[1][1], a1, b1);
            fma4(acc[1][2], a1, b2); fma4(acc[1][3], a1, b3);
            fma4(acc[2][0], a2, b0); fma4(acc[2][1], a2, b1);
            fma4(acc[2][2], a2, b2); fma4(acc[2][3], a2, b3);
            fma4(acc[3][0], a3, b0); fma4(acc[3][1], a3, b1);
            fma4(acc[3][2], a3, b2); fma4(acc[3][3], a3, b3);
        }
    }
    #pragma unroll
    for (int j = 0; j < 4; j++) {
        int wp = tr + 16 * j;
        if (wp >= WW) continue;
        #pragma unroll
        for (int l = 0; l < 4; l++) {
            int w = tw + 16 * l;
            if (w < WW) atomicAdd(&G[(size_t)c * WW * WW + wp * WW + w], acc[j][l]);
        }
    }
}

// T = imgs_flat[2304x1024] @ caps_flat[3200x1024]^T  (fp32, 128x128 tiles)
__global__ __launch_bounds__(256) void gemm_nt_kernel(
        const float* __restrict__ A, const float* __restrict__ B,
        float* __restrict__ T) {
    __shared__ __align__(16) float As[16][132];
    __shared__ __align__(16) float Bs[16][132];
    int tid = threadIdx.x;
    int m0 = blockIdx.y * 128, n0 = blockIdx.x * 128;
    int tm = tid & 15, tn = tid >> 4;
    float acc[8][8];
    #pragma unroll
    for (int j = 0; j < 8; j++)
        #pragma unroll
        for (int l = 0; l < 8; l++) acc[j][l] = 0.f;

    int lrow = tid >> 2;      // 0..63
    int lkg = tid & 3;        // 0..3  -> k-offset lkg*4
    const float* Aptr = A + (size_t)(m0 + lrow) * GK + lkg * 4;
    const float* Bptr = B + (size_t)(n0 + lrow) * GK + lkg * 4;

    for (int k0 = 0; k0 < GK; k0 += 16) {
        float4 a0 = *(const float4*)(Aptr + k0);
        float4 a1 = *(const float4*)(Aptr + k0 + (size_t)64 * GK);
        float4 b0 = *(const float4*)(Bptr + k0);
        float4 b1 = *(const float4*)(Bptr + k0 + (size_t)64 * GK);
        __syncthreads();
        As[lkg * 4 + 0][lrow] = a0.x; As[lkg * 4 + 1][lrow] = a0.y;
        As[lkg * 4 + 2][lrow] = a0.z; As[lkg * 4 + 3][lrow] = a0.w;
        As[lkg * 4 + 0][lrow + 64] = a1.x; As[lkg * 4 + 1][lrow + 64] = a1.y;
        As[lkg * 4 + 2][lrow + 64] = a1.z; As[lkg * 4 + 3][lrow + 64] = a1.w;
        Bs[lkg * 4 + 0][lrow] = b0.x; Bs[lkg * 4 + 1][lrow] = b0.y;
        Bs[lkg * 4 + 2][lrow] = b0.z; Bs[lkg * 4 + 3][lrow] = b0.w;
        Bs[lkg * 4 + 0][lrow + 64] = b1.x; Bs[lkg * 4 + 1][lrow + 64] = b1.y;
        Bs[lkg * 4 + 2][lrow + 64] = b1.z; Bs[lkg * 4 + 3][lrow + 64] = b1.w;
        __syncthreads();
        #pragma unroll
        for (int k = 0; k < 16; k++) {
            float4 av0 = *(const float4*)&As[k][tm * 4];
            float4 av1 = *(const float4*)&As[k][tm * 4 + 64];
            float4 bv0 = *(const float4*)&Bs[k][tn * 4];
            float4 bv1 = *(const float4*)&Bs[k][tn * 4 + 64];
            float am[8] = {av0.x, av0.y, av0.z, av0.w, av1.x, av1.y, av1.z, av1.w};
            float bn[8] = {bv0.x, bv0.y, bv0.z, bv0.w, bv1.x, bv1.y, bv1.z, bv1.w};
            #pragma unroll
            for (int j = 0; j < 8; j++)
                #pragma unroll
                for (int l = 0; l < 8; l++)
                    acc[j][l] = fmaf(am[j], bn[l], acc[j][l]);
        }
    }
    #pragma unroll
    for (int j = 0; j < 8; j++) {
        int m = m0 + ((j < 4) ? (tm * 4 + j) : (64 + tm * 4 + j - 4));
        float4 o0 = make_float4(acc[j][0], acc[j][1], acc[j][2], acc[j][3]);
        float4 o1 = make_float4(acc[j][4], acc[j][5], acc[j][6], acc[j][7]);
        *(float4*)&T[(size_t)m * GN + n0 + tn * 4] = o0;
        *(float4*)&T[(size_t)m * GN + n0 + 64 + tn * 4] = o1;
    }
}

// Epilogue: per (i,c) block. Wave-per-row softmax/argmax/mix -> Msh, num;
// then den2 = diag(M G M^T) small LDS matmul; write out.
__global__ __launch_bounds__(256) void epi_kernel(
        const float* __restrict__ T, const float* __restrict__ G,
        const int* __restrict__ img_lens, const int* __restrict__ cap_lens,
        const float* __restrict__ alpha,
        const float* __restrict__ invI, const float* __restrict__ invC,
        float* __restrict__ out) {
    int c = blockIdx.x, i = blockIdx.y;
    __shared__ __align__(16) float Tsh[36][52];
    __shared__ __align__(16) float Msh[48][52];
    __shared__ __align__(16) float Gsh[64][52];
    __shared__ float numSh[36];
    __shared__ float part[16][48];
    int tid = threadIdx.x;

    for (int t = tid; t < 36 * 52; t += 256) {
        int r = t / 52, w = t - r * 52;
        Tsh[r][w] = (w < WW) ? T[(size_t)(i * RR + r) * GN + c * WW + w] : 0.f;
    }
    for (int t = tid; t < 64 * 52; t += 256) {
        int rw = t / 52, cc = t - rw * 52;
        Gsh[rw][cc] = (rw < WW && cc < WW) ? G[(size_t)c * WW * WW + rw * WW + cc] : 0.f;
    }
    for (int t = tid; t < 12 * 52; t += 256) {
        Msh[36 + t / 52][t % 52] = 0.f;
    }
    __syncthreads();

    int li = img_lens[i], lc = cap_lens[c];
    float a_mix = 1.0f / (1.0f + expf(-alpha[0]));
    float oma = 1.0f - a_mix;

    int lane = tid & 63, wave = tid >> 6;
    float invCw = (lane < lc) ? invC[c * WW + lane] : 0.f;
    for (int r = wave; r < RR; r += 4) {
        float inv_ir = invI[i * RR + r];
        float Tv = (lane < WW) ? Tsh[r][lane] : 0.f;
        bool valid = (lane < lc);
        float S = valid ? (Tv * inv_ir * invCw) : -2.0f;
        // max + first-index argmax (64-lane shuffle reduce)
        float mv = S;
        int mi = valid ? lane : 63;
        #pragma unroll
        for (int off = 32; off > 0; off >>= 1) {
            float ov = __shfl_down(mv, off, 64);
            int oi = __shfl_down(mi, off, 64);
            if (ov > mv || (ov == mv && oi < mi)) { mv = ov; mi = oi; }
        }
        mv = __shfl(mv, 0, 64);
        mi = __shfl(mi, 0, 64);
        float e = valid ? expf((S - mv) * 10.0f) : 0.f;
        float s = e;
        #pragma unroll
        for (int off = 32; off > 0; off >>= 1) s += __shfl_down(s, off, 64);
        s = __shfl(s, 0, 64);
        float m = e * (a_mix / s);
        if (lane == mi) m += oma;
        if (lane < 52) Msh[r][lane] = m;
        float np = m * Tv;
        #pragma unroll
        for (int off = 32; off > 0; off >>= 1) np += __shfl_down(np, off, 64);
        if (lane == 0) numSh[r] = np;
    }
    __syncthreads();

    // quadratic form: h[j][l] = H[tr+16j][tw+16l] = sum_k M[r][k] G[w][k]
    int tr = tid & 15, tw = tid >> 4;
    float h[3][4];
    #pragma unroll
    for (int j = 0; j < 3; j++)
        #pragma unroll
        for (int l = 0; l < 4; l++) h[j][l] = 0.f;
    #pragma unroll
    for (int k4 = 0; k4 < 13; k4++) {
        float4 m0 = *(const float4*)&Msh[tr][k4 * 4];
        float4 m1 = *(const float4*)&Msh[tr + 16][k4 * 4];
        float4 m2 = *(const float4*)&Msh[tr + 32][k4 * 4];
        float4 g0 = *(const float4*)&Gsh[tw][k4 * 4];
        float4 g1 = *(const float4*)&Gsh[tw + 16][k4 * 4];
        float4 g2 = *(const float4*)&Gsh[tw + 32][k4 * 4];
        float4 g3 = *(const float4*)&Gsh[tw + 48][k4 * 4];
        fma4(h[0][0], m0, g0); fma4(h[0][1], m0, g1);
        fma4(h[0][2], m0, g2); fma4(h[0][3], m0, g3);
        fma4(h[1][0], m1, g0); fma4(h[1][1], m1, g1);
        fma4(h[1][2], m1, g2); fma4(h[1][3], m1, g3);
        fma4(h[2][0], m2, g0); fma4(h[2][1], m2, g1);
        fma4(h[2][2], m2, g2); fma4(h[2][3], m2, g3);
    }
    #pragma unroll
    for (int j = 0; j < 3; j++) {
        int r = tr + 16 * j;
        float p = 0.f;
        #pragma unroll
        for (int l = 0; l < 4; l++) p = fmaf(Msh[r][tw + 16 * l], h[j][l], p);
        part[tw][r] = p;
    }
    __syncthreads();
    if (tid < RR) {
        float den2 = 0.f;
        #pragma unroll
        for (int q = 0; q < 16; q++) den2 += part[q][tid];
        float res = (tid < li) ? (numSh[tid] / (sqrtf(den2) + EPSF)) : -1.0f;
        out[((size_t)i * BB + c) * RR + tid] = res;
    }
}

extern "C" void kernel_launch(void* const* d_in, const int* in_sizes, int n_in,
                              void* d_out, int out_size, void* d_ws, size_t ws_size,
                              hipStream_t stream) {
    const float* imgs = (const float*)d_in[0];
    const float* caps = (const float*)d_in[1];
    const int* img_lens = (const int*)d_in[2];
    const int* cap_lens = (const int*)d_in[3];
    const float* alpha = (const float*)d_in[4];
    float* out = (float*)d_out;

    float* ws = (float*)d_ws;
    float* invI = ws;                              // 2304
    float* invC = ws + BB * RR;                    // 3200
    float* G = ws + BB * RR + BB * WW;             // 160000
    float* T = G + BB * WW * WW;                   // 7372800

    hipMemsetAsync(G, 0, (size_t)BB * WW * WW * sizeof(float), stream);
    norm_kernel<<<(BB * RR + BB * WW) / 4, 256, 0, stream>>>(imgs, caps, invI, invC);
    gram_kernel<<<dim3(BB, 4), 256, 0, stream>>>(caps, G);
    gemm_nt_kernel<<<dim3(GN / 128, GM / 128), 256, 0, stream>>>(imgs, caps, T);
    epi_kernel<<<dim3(BB, BB), 256, 0, stream>>>(
        T, G, img_lens, cap_lens, alpha, invI, invC, out);
}

// Round 3
// 260.770 us; speedup vs baseline: 2.3729x; 1.4415x over previous
//
#include <hip/hip_runtime.h>
#include <math.h>

#define BB 64
#define RR 36
#define WW 50
#define DD 1024
#define EPSF 1e-8f

#define GM 2304   // 64*36
#define GN 3200   // 64*50
#define GK 1024

typedef __attribute__((ext_vector_type(8))) short bf16x8;
typedef __attribute__((ext_vector_type(4))) float f32x4;

// ws layout (floats): invI[2304] @0 | invC[3200] @2304 | G[160000] @5504 |
// T[7372800] @165504 ; then (ushort region @ float 7538304):
// Ah[2359296] | Al[2359296] | Bh[3276800] | Bl[3276800]  -> total ~52.7 MB

__device__ __forceinline__ void fma4(float& acc, const float4 a, const float4 b) {
    acc = fmaf(a.x, b.x, acc);
    acc = fmaf(a.y, b.y, acc);
    acc = fmaf(a.z, b.z, acc);
    acc = fmaf(a.w, b.w, acc);
}

__device__ __forceinline__ unsigned short f2bf(float x) {
    unsigned int u = __float_as_uint(x);
    unsigned int r = (u + 0x7fffu + ((u >> 16) & 1u)) >> 16;   // RTN-even
    return (unsigned short)r;
}
__device__ __forceinline__ float bf2f(unsigned short h) {
    return __uint_as_float(((unsigned int)h) << 16);
}

// fp32 -> (hi, lo) bf16 split, float4 per thread
__global__ __launch_bounds__(256) void convert_kernel(
        const float* __restrict__ X, unsigned short* __restrict__ H,
        unsigned short* __restrict__ L, int n4) {
    int idx = blockIdx.x * 256 + threadIdx.x;
    if (idx >= n4) return;
    float4 v = ((const float4*)X)[idx];
    float f[4] = {v.x, v.y, v.z, v.w};
    ushort4 hh, ll;
    unsigned short* hp = (unsigned short*)&hh;
    unsigned short* lp = (unsigned short*)&ll;
    #pragma unroll
    for (int j = 0; j < 4; j++) {
        unsigned short hb = f2bf(f[j]);
        float res = f[j] - bf2f(hb);
        hp[j] = hb;
        lp[j] = f2bf(res);
    }
    ((ushort4*)H)[idx] = hh;
    ((ushort4*)L)[idx] = ll;
}

// wave-per-row inverse norms: 5504 rows, 4 rows/block
__global__ __launch_bounds__(256) void norm_kernel(
        const float* __restrict__ imgs, const float* __restrict__ caps,
        float* __restrict__ invI, float* __restrict__ invC) {
    int lane = threadIdx.x & 63, wv = threadIdx.x >> 6;
    int row = blockIdx.x * 4 + wv;
    const float* src;
    float* dst;
    if (row < BB * RR) { src = imgs + (size_t)row * DD; dst = invI + row; }
    else { int q = row - BB * RR; src = caps + (size_t)q * DD; dst = invC + q; }
    float ss = 0.f;
    #pragma unroll
    for (int j = 0; j < 4; j++) {
        float4 v = ((const float4*)src)[lane + 64 * j];
        ss += v.x * v.x + v.y * v.y + v.z * v.z + v.w * v.w;
    }
    #pragma unroll
    for (int off = 32; off > 0; off >>= 1) ss += __shfl_down(ss, off, 64);
    if (lane == 0) *dst = 1.0f / (sqrtf(ss) + EPSF);
}

// Gram: grid (c=64, kq=4); atomicAdd into zeroed G.
__global__ __launch_bounds__(256) void gram_kernel(
        const float* __restrict__ caps, float* __restrict__ G) {
    int c = blockIdx.x, kq = blockIdx.y;
    const float* cap = caps + (size_t)c * WW * DD + kq * 256;
    __shared__ __align__(16) float cs[64][68];
    int tid = threadIdx.x;
    int tr = tid & 15, tw = tid >> 4;
    float acc[4][4];
    #pragma unroll
    for (int a = 0; a < 4; a++)
        #pragma unroll
        for (int b = 0; b < 4; b++) acc[a][b] = 0.f;

    for (int d0 = 0; d0 < 256; d0 += 64) {
        __syncthreads();
        for (int t = tid; t < 64 * 16; t += 256) {
            int rw = t >> 4, c4 = t & 15;
            float4 v = make_float4(0.f, 0.f, 0.f, 0.f);
            if (rw < WW) v = *(const float4*)(cap + (size_t)rw * DD + d0 + c4 * 4);
            *(float4*)&cs[rw][c4 * 4] = v;
        }
        __syncthreads();
        #pragma unroll 4
        for (int k4 = 0; k4 < 16; k4++) {
            float4 a0 = *(const float4*)&cs[tr][k4 * 4];
            float4 a1 = *(const float4*)&cs[tr + 16][k4 * 4];
            float4 a2 = *(const float4*)&cs[tr + 32][k4 * 4];
            float4 a3 = *(const float4*)&cs[tr + 48][k4 * 4];
            float4 b0 = *(const float4*)&cs[tw][k4 * 4];
            float4 b1 = *(const float4*)&cs[tw + 16][k4 * 4];
            float4 b2 = *(const float4*)&cs[tw + 32][k4 * 4];
            float4 b3 = *(const float4*)&cs[tw + 48][k4 * 4];
            fma4(acc[0][0], a0, b0); fma4(acc[0][1], a0, b1);
            fma4(acc[0][2], a0, b2); fma4(acc[0][3], a0, b3);
            fma4(acc[1][0], a1, b0); fma4(acc[1][1], a1, b1);
            fma4(acc[1][2], a1, b2); fma4(acc[1][3], a1, b3);
            fma4(acc[2][0], a2, b0); fma4(acc[2][1], a2, b1);
            fma4(acc[2][2], a2, b2); fma4(acc[2][3], a2, b3);
            fma4(acc[3][0], a3, b0); fma4(acc[3][1], a3, b1);
            fma4(acc[3][2], a3, b2); fma4(acc[3][3], a3, b3);
        }
    }
    #pragma unroll
    for (int j = 0; j < 4; j++) {
        int wp = tr + 16 * j;
        if (wp >= WW) continue;
        #pragma unroll
        for (int l = 0; l < 4; l++) {
            int w = tw + 16 * l;
            if (w < WW) atomicAdd(&G[(size_t)c * WW * WW + wp * WW + w], acc[j][l]);
        }
    }
}

// T = A[2304x1024] @ B[3200x1024]^T via 3-pass hi/lo bf16 MFMA.
// Block tile 64(M) x 128(N), BK=32, 4 waves each 32x64.
__global__ __launch_bounds__(256) void gemm_mfma_kernel(
        const unsigned short* __restrict__ Ah, const unsigned short* __restrict__ Al,
        const unsigned short* __restrict__ Bh, const unsigned short* __restrict__ Bl,
        float* __restrict__ T) {
    __shared__ unsigned short sAh[64 * 32], sAl[64 * 32];
    __shared__ unsigned short sBh[128 * 32], sBl[128 * 32];
    int tid = threadIdx.x;
    int lane = tid & 63, wv = tid >> 6;
    int m0 = blockIdx.y * 64, n0 = blockIdx.x * 128;
    int rw = (wv & 1) * 32;        // wave row base within tile
    int cw = (wv >> 1) * 64;       // wave col base within tile

    f32x4 acc[2][4] = {};

    int srow = lane >> 2;           // 0..15 row within 16-row segment
    int scol = (lane & 3) * 8;      // bf16 elem offset within 32-wide k
    int fm = lane & 15;
    int fk = (lane >> 4) * 8;

    for (int k0 = 0; k0 < GK; k0 += 32) {
        __syncthreads();
        {   // A: 4 segments of 16 rows; wave wv stages segment wv (hi+lo)
            int arow = m0 + wv * 16 + srow;
            size_t g = (size_t)arow * GK + k0 + scol;
            __builtin_amdgcn_global_load_lds(
                (const __attribute__((address_space(1))) void*)(Ah + g),
                (__attribute__((address_space(3))) void*)(sAh + wv * 512), 16, 0, 0);
            __builtin_amdgcn_global_load_lds(
                (const __attribute__((address_space(1))) void*)(Al + g),
                (__attribute__((address_space(3))) void*)(sAl + wv * 512), 16, 0, 0);
        }
        #pragma unroll
        for (int j = 0; j < 2; j++) {   // B: 8 segments; wave stages 2w, 2w+1
            int s = wv * 2 + j;
            int brow = n0 + s * 16 + srow;
            size_t g = (size_t)brow * GK + k0 + scol;
            __builtin_amdgcn_global_load_lds(
                (const __attribute__((address_space(1))) void*)(Bh + g),
                (__attribute__((address_space(3))) void*)(sBh + s * 512), 16, 0, 0);
            __builtin_amdgcn_global_load_lds(
                (const __attribute__((address_space(1))) void*)(Bl + g),
                (__attribute__((address_space(3))) void*)(sBl + s * 512), 16, 0, 0);
        }
        __syncthreads();

        bf16x8 fah[2], fal[2], fbh[4], fbl[4];
        #pragma unroll
        for (int t = 0; t < 2; t++) {
            int off = (rw + t * 16 + fm) * 32 + fk;
            fah[t] = *(const bf16x8*)&sAh[off];
            fal[t] = *(const bf16x8*)&sAl[off];
        }
        #pragma unroll
        for (int t = 0; t < 4; t++) {
            int off = (cw + t * 16 + fm) * 32 + fk;
            fbh[t] = *(const bf16x8*)&sBh[off];
            fbl[t] = *(const bf16x8*)&sBl[off];
        }
        #pragma unroll
        for (int mt = 0; mt < 2; mt++)
            #pragma unroll
            for (int nt = 0; nt < 4; nt++) {
                acc[mt][nt] = __builtin_amdgcn_mfma_f32_16x16x32_bf16(
                    fah[mt], fbh[nt], acc[mt][nt], 0, 0, 0);
                acc[mt][nt] = __builtin_amdgcn_mfma_f32_16x16x32_bf16(
                    fah[mt], fbl[nt], acc[mt][nt], 0, 0, 0);
                acc[mt][nt] = __builtin_amdgcn_mfma_f32_16x16x32_bf16(
                    fal[mt], fbh[nt], acc[mt][nt], 0, 0, 0);
            }
    }

    // C/D layout: col = lane&15, row = (lane>>4)*4 + reg  [m89/m91]
    int orow0 = m0 + rw + (lane >> 4) * 4;
    int ocol0 = n0 + cw + (lane & 15);
    #pragma unroll
    for (int mt = 0; mt < 2; mt++)
        #pragma unroll
        for (int nt = 0; nt < 4; nt++)
            #pragma unroll
            for (int v = 0; v < 4; v++)
                T[(size_t)(orow0 + mt * 16 + v) * GN + ocol0 + nt * 16] = acc[mt][nt][v];
}

// Epilogue: per (i,c) block. Wave-per-row softmax/argmax/mix -> Msh, num;
// then den2 = diag(M G M^T) small LDS matmul; write out.
__global__ __launch_bounds__(256) void epi_kernel(
        const float* __restrict__ T, const float* __restrict__ G,
        const int* __restrict__ img_lens, const int* __restrict__ cap_lens,
        const float* __restrict__ alpha,
        const float* __restrict__ invI, const float* __restrict__ invC,
        float* __restrict__ out) {
    int c = blockIdx.x, i = blockIdx.y;
    __shared__ __align__(16) float Tsh[36][52];
    __shared__ __align__(16) float Msh[48][52];
    __shared__ __align__(16) float Gsh[64][52];
    __shared__ float numSh[36];
    __shared__ float part[16][48];
    int tid = threadIdx.x;

    for (int t = tid; t < 36 * 52; t += 256) {
        int r = t / 52, w = t - r * 52;
        Tsh[r][w] = (w < WW) ? T[(size_t)(i * RR + r) * GN + c * WW + w] : 0.f;
    }
    for (int t = tid; t < 64 * 52; t += 256) {
        int rw = t / 52, cc = t - rw * 52;
        Gsh[rw][cc] = (rw < WW && cc < WW) ? G[(size_t)c * WW * WW + rw * WW + cc] : 0.f;
    }
    for (int t = tid; t < 12 * 52; t += 256) {
        Msh[36 + t / 52][t % 52] = 0.f;
    }
    __syncthreads();

    int li = img_lens[i], lc = cap_lens[c];
    float a_mix = 1.0f / (1.0f + expf(-alpha[0]));
    float oma = 1.0f - a_mix;

    int lane = tid & 63, wave = tid >> 6;
    float invCw = (lane < lc) ? invC[c * WW + lane] : 0.f;
    for (int r = wave; r < RR; r += 4) {
        float inv_ir = invI[i * RR + r];
        float Tv = (lane < WW) ? Tsh[r][lane] : 0.f;
        bool valid = (lane < lc);
        float S = valid ? (Tv * inv_ir * invCw) : -2.0f;
        float mv = S;
        int mi = valid ? lane : 63;
        #pragma unroll
        for (int off = 32; off > 0; off >>= 1) {
            float ov = __shfl_down(mv, off, 64);
            int oi = __shfl_down(mi, off, 64);
            if (ov > mv || (ov == mv && oi < mi)) { mv = ov; mi = oi; }
        }
        mv = __shfl(mv, 0, 64);
        mi = __shfl(mi, 0, 64);
        float e = valid ? expf((S - mv) * 10.0f) : 0.f;
        float s = e;
        #pragma unroll
        for (int off = 32; off > 0; off >>= 1) s += __shfl_down(s, off, 64);
        s = __shfl(s, 0, 64);
        float m = e * (a_mix / s);
        if (lane == mi) m += oma;
        if (lane < 52) Msh[r][lane] = m;
        float np = m * Tv;
        #pragma unroll
        for (int off = 32; off > 0; off >>= 1) np += __shfl_down(np, off, 64);
        if (lane == 0) numSh[r] = np;
    }
    __syncthreads();

    int tr = tid & 15, tw = tid >> 4;
    float h[3][4];
    #pragma unroll
    for (int j = 0; j < 3; j++)
        #pragma unroll
        for (int l = 0; l < 4; l++) h[j][l] = 0.f;
    #pragma unroll
    for (int k4 = 0; k4 < 13; k4++) {
        float4 m0 = *(const float4*)&Msh[tr][k4 * 4];
        float4 m1 = *(const float4*)&Msh[tr + 16][k4 * 4];
        float4 m2 = *(const float4*)&Msh[tr + 32][k4 * 4];
        float4 g0 = *(const float4*)&Gsh[tw][k4 * 4];
        float4 g1 = *(const float4*)&Gsh[tw + 16][k4 * 4];
        float4 g2 = *(const float4*)&Gsh[tw + 32][k4 * 4];
        float4 g3 = *(const float4*)&Gsh[tw + 48][k4 * 4];
        fma4(h[0][0], m0, g0); fma4(h[0][1], m0, g1);
        fma4(h[0][2], m0, g2); fma4(h[0][3], m0, g3);
        fma4(h[1][0], m1, g0); fma4(h[1][1], m1, g1);
        fma4(h[1][2], m1, g2); fma4(h[1][3], m1, g3);
        fma4(h[2][0], m2, g0); fma4(h[2][1], m2, g1);
        fma4(h[2][2], m2, g2); fma4(h[2][3], m2, g3);
    }
    #pragma unroll
    for (int j = 0; j < 3; j++) {
        int r = tr + 16 * j;
        float p = 0.f;
        #pragma unroll
        for (int l = 0; l < 4; l++) p = fmaf(Msh[r][tw + 16 * l], h[j][l], p);
        part[tw][r] = p;
    }
    __syncthreads();
    if (tid < RR) {
        float den2 = 0.f;
        #pragma unroll
        for (int q = 0; q < 16; q++) den2 += part[q][tid];
        float res = (tid < li) ? (numSh[tid] / (sqrtf(den2) + EPSF)) : -1.0f;
        out[((size_t)i * BB + c) * RR + tid] = res;
    }
}

extern "C" void kernel_launch(void* const* d_in, const int* in_sizes, int n_in,
                              void* d_out, int out_size, void* d_ws, size_t ws_size,
                              hipStream_t stream) {
    const float* imgs = (const float*)d_in[0];
    const float* caps = (const float*)d_in[1];
    const int* img_lens = (const int*)d_in[2];
    const int* cap_lens = (const int*)d_in[3];
    const float* alpha = (const float*)d_in[4];
    float* out = (float*)d_out;

    float* ws = (float*)d_ws;
    float* invI = ws;                              // 2304
    float* invC = ws + BB * RR;                    // 3200
    float* G = ws + BB * RR + BB * WW;             // 160000
    float* T = G + BB * WW * WW;                   // 7372800
    unsigned short* Ah = (unsigned short*)(T + (size_t)GM * GN);
    unsigned short* Al = Ah + (size_t)GM * GK;
    unsigned short* Bh = Al + (size_t)GM * GK;
    unsigned short* Bl = Bh + (size_t)GN * GK;

    hipMemsetAsync(G, 0, (size_t)BB * WW * WW * sizeof(float), stream);
    convert_kernel<<<(GM * GK / 4 + 255) / 256, 256, 0, stream>>>(imgs, Ah, Al, GM * GK / 4);
    convert_kernel<<<(GN * GK / 4 + 255) / 256, 256, 0, stream>>>(caps, Bh, Bl, GN * GK / 4);
    norm_kernel<<<(BB * RR + BB * WW) / 4, 256, 0, stream>>>(imgs, caps, invI, invC);
    gram_kernel<<<dim3(BB, 4), 256, 0, stream>>>(caps, G);
    gemm_mfma_kernel<<<dim3(GN / 128, GM / 64), 256, 0, stream>>>(Ah, Al, Bh, Bl, T);
    epi_kernel<<<dim3(BB, BB), 256, 0, stream>>>(
        T, G, img_lens, cap_lens, alpha, invI, invC, out);
}

// Round 4
// 230.535 us; speedup vs baseline: 2.6841x; 1.1312x over previous
//
#include <hip/hip_runtime.h>
#include <math.h>

#define BB 64
#define RR 36
#define WW 50
#define DD 1024
#define EPSF 1e-8f

#define GM 2304   // 64*36
#define GN 3200   // 64*50
#define GK 1024

typedef __attribute__((ext_vector_type(8))) short bf16x8;
typedef __attribute__((ext_vector_type(4))) float f32x4;

__device__ __forceinline__ void fma4(float& acc, const float4 a, const float4 b) {
    acc = fmaf(a.x, b.x, acc);
    acc = fmaf(a.y, b.y, acc);
    acc = fmaf(a.z, b.z, acc);
    acc = fmaf(a.w, b.w, acc);
}

__device__ __forceinline__ unsigned short f2bf(float x) {
    unsigned int u = __float_as_uint(x);
    unsigned int r = (u + 0x7fffu + ((u >> 16) & 1u)) >> 16;   // RTN-even
    return (unsigned short)r;
}
__device__ __forceinline__ float bf2f(unsigned short h) {
    return __uint_as_float(((unsigned int)h) << 16);
}

// fp32 -> (hi, lo) bf16 split, float4 per thread
__global__ __launch_bounds__(256) void convert_kernel(
        const float* __restrict__ X, unsigned short* __restrict__ H,
        unsigned short* __restrict__ L, int n4) {
    int idx = blockIdx.x * 256 + threadIdx.x;
    if (idx >= n4) return;
    float4 v = ((const float4*)X)[idx];
    float f[4] = {v.x, v.y, v.z, v.w};
    ushort4 hh, ll;
    unsigned short* hp = (unsigned short*)&hh;
    unsigned short* lp = (unsigned short*)&ll;
    #pragma unroll
    for (int j = 0; j < 4; j++) {
        unsigned short hb = f2bf(f[j]);
        float res = f[j] - bf2f(hb);
        hp[j] = hb;
        lp[j] = f2bf(res);
    }
    ((ushort4*)H)[idx] = hh;
    ((ushort4*)L)[idx] = ll;
}

// wave-per-row inverse norms
__global__ __launch_bounds__(256) void norm_kernel(
        const float* __restrict__ imgs, const float* __restrict__ caps,
        float* __restrict__ invI, float* __restrict__ invC) {
    int lane = threadIdx.x & 63, wv = threadIdx.x >> 6;
    int row = blockIdx.x * 4 + wv;
    const float* src;
    float* dst;
    if (row < BB * RR) { src = imgs + (size_t)row * DD; dst = invI + row; }
    else { int q = row - BB * RR; src = caps + (size_t)q * DD; dst = invC + q; }
    float ss = 0.f;
    #pragma unroll
    for (int j = 0; j < 4; j++) {
        float4 v = ((const float4*)src)[lane + 64 * j];
        ss += v.x * v.x + v.y * v.y + v.z * v.z + v.w * v.w;
    }
    #pragma unroll
    for (int off = 32; off > 0; off >>= 1) ss += __shfl_down(ss, off, 64);
    if (lane == 0) *dst = 1.0f / (sqrtf(ss) + EPSF);
}

// Gram: grid (c=64, kq=4); atomicAdd into zeroed G.
__global__ __launch_bounds__(256) void gram_kernel(
        const float* __restrict__ caps, float* __restrict__ G) {
    int c = blockIdx.x, kq = blockIdx.y;
    const float* cap = caps + (size_t)c * WW * DD + kq * 256;
    __shared__ __align__(16) float cs[64][68];
    int tid = threadIdx.x;
    int tr = tid & 15, tw = tid >> 4;
    float acc[4][4];
    #pragma unroll
    for (int a = 0; a < 4; a++)
        #pragma unroll
        for (int b = 0; b < 4; b++) acc[a][b] = 0.f;

    for (int d0 = 0; d0 < 256; d0 += 64) {
        __syncthreads();
        for (int t = tid; t < 64 * 16; t += 256) {
            int rw = t >> 4, c4 = t & 15;
            float4 v = make_float4(0.f, 0.f, 0.f, 0.f);
            if (rw < WW) v = *(const float4*)(cap + (size_t)rw * DD + d0 + c4 * 4);
            *(float4*)&cs[rw][c4 * 4] = v;
        }
        __syncthreads();
        #pragma unroll 4
        for (int k4 = 0; k4 < 16; k4++) {
            float4 a0 = *(const float4*)&cs[tr][k4 * 4];
            float4 a1 = *(const float4*)&cs[tr + 16][k4 * 4];
            float4 a2 = *(const float4*)&cs[tr + 32][k4 * 4];
            float4 a3 = *(const float4*)&cs[tr + 48][k4 * 4];
            float4 b0 = *(const float4*)&cs[tw][k4 * 4];
            float4 b1 = *(const float4*)&cs[tw + 16][k4 * 4];
            float4 b2 = *(const float4*)&cs[tw + 32][k4 * 4];
            float4 b3 = *(const float4*)&cs[tw + 48][k4 * 4];
            fma4(acc[0][0], a0, b0); fma4(acc[0][1], a0, b1);
            fma4(acc[0][2], a0, b2); fma4(acc[0][3], a0, b3);
            fma4(acc[1][0], a1, b0); fma4(acc[1][1], a1, b1);
            fma4(acc[1][2], a1, b2); fma4(acc[1][3], a1, b3);
            fma4(acc[2][0], a2, b0); fma4(acc[2][1], a2, b1);
            fma4(acc[2][2], a2, b2); fma4(acc[2][3], a2, b3);
            fma4(acc[3][0], a3, b0); fma4(acc[3][1], a3, b1);
            fma4(acc[3][2], a3, b2); fma4(acc[3][3], a3, b3);
        }
    }
    #pragma unroll
    for (int j = 0; j < 4; j++) {
        int wp = tr + 16 * j;
        if (wp >= WW) continue;
        #pragma unroll
        for (int l = 0; l < 4; l++) {
            int w = tw + 16 * l;
            if (w < WW) atomicAdd(&G[(size_t)c * WW * WW + wp * WW + w], acc[j][l]);
        }
    }
}

// G fp32 -> padded 64x64 bf16 hi/lo per caption
__global__ __launch_bounds__(256) void g2bf_kernel(
        const float* __restrict__ G, unsigned short* __restrict__ Gh,
        unsigned short* __restrict__ Gl) {
    int c = blockIdx.x;
    int tid = threadIdx.x;
    for (int t = tid; t < 4096; t += 256) {
        int w = t >> 6, wp = t & 63;
        float g = (w < WW && wp < WW) ? G[(size_t)c * WW * WW + w * WW + wp] : 0.f;
        unsigned short h = f2bf(g);
        Gh[(size_t)c * 4096 + t] = h;
        Gl[(size_t)c * 4096 + t] = f2bf(g - bf2f(h));
    }
}

// T = A[2304x1024] @ B[3200x1024]^T via 3-pass hi/lo bf16 MFMA.
// Block tile 128x128, BK=32, 4 waves each 64x64.
__global__ __launch_bounds__(256) void gemm_mfma_kernel(
        const unsigned short* __restrict__ Ah, const unsigned short* __restrict__ Al,
        const unsigned short* __restrict__ Bh, const unsigned short* __restrict__ Bl,
        float* __restrict__ T) {
    __shared__ __align__(16) unsigned short sAh[128 * 32], sAl[128 * 32];
    __shared__ __align__(16) unsigned short sBh[128 * 32], sBl[128 * 32];
    int tid = threadIdx.x;
    int lane = tid & 63, wv = tid >> 6;
    int m0 = blockIdx.y * 128, n0 = blockIdx.x * 128;
    int rw = (wv & 1) * 64;        // wave row base
    int cw = (wv >> 1) * 64;       // wave col base

    f32x4 acc[4][4] = {};

    int srow = lane >> 2;          // 0..15 row within 16-row segment
    int scol = (lane & 3) * 8;     // ushort offset within 32-wide k
    int fm = lane & 15;
    int fk = (lane >> 4) * 8;

    for (int k0 = 0; k0 < GK; k0 += 32) {
        __syncthreads();
        #pragma unroll
        for (int j = 0; j < 2; j++) {
            int seg = wv * 2 + j;                 // 16-row segment 0..7
            int row = seg * 16 + srow;
            size_t ga = (size_t)(m0 + row) * GK + k0 + scol;
            size_t gb = (size_t)(n0 + row) * GK + k0 + scol;
            __builtin_amdgcn_global_load_lds(
                (const __attribute__((address_space(1))) void*)(Ah + ga),
                (__attribute__((address_space(3))) void*)(sAh + seg * 512), 16, 0, 0);
            __builtin_amdgcn_global_load_lds(
                (const __attribute__((address_space(1))) void*)(Al + ga),
                (__attribute__((address_space(3))) void*)(sAl + seg * 512), 16, 0, 0);
            __builtin_amdgcn_global_load_lds(
                (const __attribute__((address_space(1))) void*)(Bh + gb),
                (__attribute__((address_space(3))) void*)(sBh + seg * 512), 16, 0, 0);
            __builtin_amdgcn_global_load_lds(
                (const __attribute__((address_space(1))) void*)(Bl + gb),
                (__attribute__((address_space(3))) void*)(sBl + seg * 512), 16, 0, 0);
        }
        __syncthreads();

        bf16x8 fah[4], fal[4], fbh[4], fbl[4];
        #pragma unroll
        for (int t = 0; t < 4; t++) {
            int offa = (rw + t * 16 + fm) * 32 + fk;
            int offb = (cw + t * 16 + fm) * 32 + fk;
            fah[t] = *(const bf16x8*)&sAh[offa];
            fal[t] = *(const bf16x8*)&sAl[offa];
            fbh[t] = *(const bf16x8*)&sBh[offb];
            fbl[t] = *(const bf16x8*)&sBl[offb];
        }
        #pragma unroll
        for (int mt = 0; mt < 4; mt++)
            #pragma unroll
            for (int nt = 0; nt < 4; nt++) {
                acc[mt][nt] = __builtin_amdgcn_mfma_f32_16x16x32_bf16(
                    fah[mt], fbh[nt], acc[mt][nt], 0, 0, 0);
                acc[mt][nt] = __builtin_amdgcn_mfma_f32_16x16x32_bf16(
                    fah[mt], fbl[nt], acc[mt][nt], 0, 0, 0);
                acc[mt][nt] = __builtin_amdgcn_mfma_f32_16x16x32_bf16(
                    fal[mt], fbh[nt], acc[mt][nt], 0, 0, 0);
            }
    }

    int orow0 = m0 + rw + (lane >> 4) * 4;
    int ocol0 = n0 + cw + (lane & 15);
    #pragma unroll
    for (int mt = 0; mt < 4; mt++)
        #pragma unroll
        for (int nt = 0; nt < 4; nt++)
            #pragma unroll
            for (int v = 0; v < 4; v++)
                T[(size_t)(orow0 + mt * 16 + v) * GN + ocol0 + nt * 16] = acc[mt][nt][v];
}

// Epilogue v2: grid (c=64, ig=8); each block handles 8 images.
// Per image: stage T -> half-wave-per-row softmax/argmax/mix -> M (fp32 + bf16
// hi/lo) -> H = M*G via 3-pass MFMA -> den2 = rowsum(M*H) -> out.
#define MST 72   // sMh/sMl row stride (ushorts): 144B, 16B-aligned, spreads banks
__global__ __launch_bounds__(256) void epi_kernel(
        const float* __restrict__ T,
        const unsigned short* __restrict__ Gh, const unsigned short* __restrict__ Gl,
        const int* __restrict__ img_lens, const int* __restrict__ cap_lens,
        const float* __restrict__ alpha,
        const float* __restrict__ invI, const float* __restrict__ invC,
        float* __restrict__ out) {
    int c = blockIdx.x, ig = blockIdx.y;
    __shared__ __align__(16) unsigned short sGh[64 * 64], sGl[64 * 64];
    __shared__ __align__(16) unsigned short sMh[48 * MST], sMl[48 * MST];
    __shared__ __align__(16) float Msh[48 * 64];
    __shared__ __align__(16) float Tsh[36][52];
    __shared__ __align__(16) float Hsh[48][68];
    __shared__ float numSh[36];
    __shared__ float part[36][4];

    int tid = threadIdx.x;
    int lane = tid & 63, wv = tid >> 6;
    int fm = lane & 15, fk8 = (lane >> 4) * 8;
    int half = lane >> 5, l5 = lane & 31;

    // stage G (bf16 hi/lo), 8KB each
    {
        const uint4* gh = (const uint4*)(Gh + (size_t)c * 4096);
        const uint4* gl = (const uint4*)(Gl + (size_t)c * 4096);
        ((uint4*)sGh)[tid] = gh[tid];
        ((uint4*)sGh)[tid + 256] = gh[tid + 256];
        ((uint4*)sGl)[tid] = gl[tid];
        ((uint4*)sGl)[tid + 256] = gl[tid + 256];
    }
    // zero M pad rows 36..47
    for (int t = tid; t < 12 * MST; t += 256) {
        sMh[36 * MST + t] = 0; sMl[36 * MST + t] = 0;
    }
    for (int t = tid; t < 12 * 64; t += 256) Msh[36 * 64 + t] = 0.f;
    __syncthreads();

    // hoist G fragments (wave wv = n-tile wv)
    bf16x8 gfh[2], gfl[2];
    #pragma unroll
    for (int ks = 0; ks < 2; ks++) {
        int off = (wv * 16 + fm) * 64 + ks * 32 + fk8;
        gfh[ks] = *(const bf16x8*)&sGh[off];
        gfl[ks] = *(const bf16x8*)&sGl[off];
    }

    int lc = cap_lens[c];
    float a_mix = 1.0f / (1.0f + __expf(-alpha[0]));
    float oma = 1.0f - a_mix;
    float invC0 = invC[c * WW + l5];
    float invC1 = (l5 + 32 < WW) ? invC[c * WW + l5 + 32] : 0.f;
    bool v0 = l5 < lc, v1 = (l5 + 32) < lc;

    for (int ii = 0; ii < 8; ii++) {
        int i = ig * 8 + ii;
        int li = img_lens[i];
        // stage T tile
        for (int t = tid; t < 36 * 52; t += 256) {
            int r = t / 52, w = t - r * 52;
            Tsh[r][w] = (w < WW) ? T[(size_t)(i * RR + r) * GN + c * WW + w] : 0.f;
        }
        __syncthreads();

        // softmax: half-wave per row
        for (int r = wv * 2 + half; r < RR; r += 8) {
            float inv_ir = invI[i * RR + r];
            float T0 = Tsh[r][l5];
            float T1 = (l5 + 32 < WW) ? Tsh[r][l5 + 32] : 0.f;
            float S0 = v0 ? (T0 * inv_ir * invC0) : -2.f;
            float S1 = v1 ? (T1 * inv_ir * invC1) : -2.f;
            float mv; int mi;
            if (S1 > S0) { mv = S1; mi = l5 + 32; } else { mv = S0; mi = l5; }
            #pragma unroll
            for (int m = 1; m < 32; m <<= 1) {
                float ov = __shfl_xor(mv, m, 32);
                int oi = __shfl_xor(mi, m, 32);
                if (ov > mv || (ov == mv && oi < mi)) { mv = ov; mi = oi; }
            }
            float e0 = v0 ? __expf((S0 - mv) * 10.f) : 0.f;
            float e1 = v1 ? __expf((S1 - mv) * 10.f) : 0.f;
            float ss = e0 + e1, nm = fmaf(e0, T0, e1 * T1);
            #pragma unroll
            for (int m = 1; m < 32; m <<= 1) {
                ss += __shfl_xor(ss, m, 32);
                nm += __shfl_xor(nm, m, 32);
            }
            float scale = a_mix / ss;
            float m0 = e0 * scale + (l5 == mi ? oma : 0.f);
            float m1 = e1 * scale + (l5 + 32 == mi ? oma : 0.f);
            if (l5 == 0) numSh[r] = fmaf(nm, scale, oma * Tsh[r][mi]);
            Msh[r * 64 + l5] = m0;
            Msh[r * 64 + l5 + 32] = m1;
            unsigned short h0 = f2bf(m0), h1 = f2bf(m1);
            sMh[r * MST + l5] = h0;
            sMl[r * MST + l5] = f2bf(m0 - bf2f(h0));
            sMh[r * MST + l5 + 32] = h1;
            sMl[r * MST + l5 + 32] = f2bf(m1 - bf2f(h1));
        }
        __syncthreads();

        // H = M * G via MFMA (3-pass hi/lo); wave wv owns n-tile wv
        #pragma unroll
        for (int mt = 0; mt < 3; mt++) {
            f32x4 acc = {0.f, 0.f, 0.f, 0.f};
            #pragma unroll
            for (int ks = 0; ks < 2; ks++) {
                int off = (mt * 16 + fm) * MST + ks * 32 + fk8;
                bf16x8 mh = *(const bf16x8*)&sMh[off];
                bf16x8 ml = *(const bf16x8*)&sMl[off];
                acc = __builtin_amdgcn_mfma_f32_16x16x32_bf16(mh, gfh[ks], acc, 0, 0, 0);
                acc = __builtin_amdgcn_mfma_f32_16x16x32_bf16(mh, gfl[ks], acc, 0, 0, 0);
                acc = __builtin_amdgcn_mfma_f32_16x16x32_bf16(ml, gfh[ks], acc, 0, 0, 0);
            }
            #pragma unroll
            for (int v = 0; v < 4; v++)
                Hsh[mt * 16 + (lane >> 4) * 4 + v][wv * 16 + fm] = acc[v];
        }
        __syncthreads();

        // den2 = rowsum(M .* H)
        if (tid < 144) {
            int r = tid >> 2, j = tid & 3;
            const float4* mrow = (const float4*)&Msh[r * 64 + j * 16];
            const float4* hrow = (const float4*)&Hsh[r][j * 16];
            float p = 0.f;
            #pragma unroll
            for (int q = 0; q < 4; q++) fma4(p, mrow[q], hrow[q]);
            part[r][j] = p;
        }
        __syncthreads();
        if (tid < RR) {
            float den2 = part[tid][0] + part[tid][1] + part[tid][2] + part[tid][3];
            float res = (tid < li) ? (numSh[tid] / (sqrtf(den2) + EPSF)) : -1.0f;
            out[((size_t)i * BB + c) * RR + tid] = res;
        }
        __syncthreads();
    }
}

extern "C" void kernel_launch(void* const* d_in, const int* in_sizes, int n_in,
                              void* d_out, int out_size, void* d_ws, size_t ws_size,
                              hipStream_t stream) {
    const float* imgs = (const float*)d_in[0];
    const float* caps = (const float*)d_in[1];
    const int* img_lens = (const int*)d_in[2];
    const int* cap_lens = (const int*)d_in[3];
    const float* alpha = (const float*)d_in[4];
    float* out = (float*)d_out;

    float* ws = (float*)d_ws;
    float* invI = ws;                              // 2304
    float* invC = ws + BB * RR;                    // 3200
    float* G = ws + BB * RR + BB * WW;             // 160000
    float* T = G + BB * WW * WW;                   // 7372800
    unsigned short* Ah = (unsigned short*)(T + (size_t)GM * GN);
    unsigned short* Al = Ah + (size_t)GM * GK;
    unsigned short* Bh = Al + (size_t)GM * GK;
    unsigned short* Bl = Bh + (size_t)GN * GK;
    unsigned short* Gbh = Bl + (size_t)GN * GK;    // 64*4096
    unsigned short* Gbl = Gbh + (size_t)BB * 4096;

    hipMemsetAsync(G, 0, (size_t)BB * WW * WW * sizeof(float), stream);
    convert_kernel<<<(GM * GK / 4 + 255) / 256, 256, 0, stream>>>(imgs, Ah, Al, GM * GK / 4);
    convert_kernel<<<(GN * GK / 4 + 255) / 256, 256, 0, stream>>>(caps, Bh, Bl, GN * GK / 4);
    norm_kernel<<<(BB * RR + BB * WW) / 4, 256, 0, stream>>>(imgs, caps, invI, invC);
    gram_kernel<<<dim3(BB, 4), 256, 0, stream>>>(caps, G);
    g2bf_kernel<<<BB, 256, 0, stream>>>(G, Gbh, Gbl);
    gemm_mfma_kernel<<<dim3(GN / 128, GM / 128), 256, 0, stream>>>(Ah, Al, Bh, Bl, T);
    epi_kernel<<<dim3(BB, 8), 256, 0, stream>>>(
        T, Gbh, Gbl, img_lens, cap_lens, alpha, invI, invC, out);
}

// Round 5
// 200.665 us; speedup vs baseline: 3.0837x; 1.1489x over previous
//
#include <hip/hip_runtime.h>
#include <math.h>

#define BB 64
#define RR 36
#define WW 50
#define DD 1024
#define EPSF 1e-8f

#define GM 2304   // 64*36
#define GN 3200   // 64*50
#define GK 1024

typedef __attribute__((ext_vector_type(8))) short bf16x8;
typedef __attribute__((ext_vector_type(4))) float f32x4;

__device__ __forceinline__ void fma4(float& acc, const float4 a, const float4 b) {
    acc = fmaf(a.x, b.x, acc);
    acc = fmaf(a.y, b.y, acc);
    acc = fmaf(a.z, b.z, acc);
    acc = fmaf(a.w, b.w, acc);
}

__device__ __forceinline__ unsigned short f2bf(float x) {
    unsigned int u = __float_as_uint(x);
    unsigned int r = (u + 0x7fffu + ((u >> 16) & 1u)) >> 16;   // RTN-even
    return (unsigned short)r;
}
__device__ __forceinline__ float bf2f(unsigned short h) {
    return __uint_as_float(((unsigned int)h) << 16);
}

// Fused: fp32 -> (hi,lo) bf16 split + inverse L2 norm. One block per row (1024
// elems, 256 threads x float4).
__global__ __launch_bounds__(256) void convert_norm_kernel(
        const float* __restrict__ X, unsigned short* __restrict__ H,
        unsigned short* __restrict__ L, float* __restrict__ invN) {
    int row = blockIdx.x, tid = threadIdx.x;
    size_t idx = (size_t)row * 256 + tid;
    float4 v = ((const float4*)X)[idx];
    float f[4] = {v.x, v.y, v.z, v.w};
    ushort4 hh, ll;
    unsigned short* hp = (unsigned short*)&hh;
    unsigned short* lp = (unsigned short*)&ll;
    float ss = 0.f;
    #pragma unroll
    for (int j = 0; j < 4; j++) {
        unsigned short hb = f2bf(f[j]);
        hp[j] = hb;
        lp[j] = f2bf(f[j] - bf2f(hb));
        ss = fmaf(f[j], f[j], ss);
    }
    ((ushort4*)H)[idx] = hh;
    ((ushort4*)L)[idx] = ll;
    #pragma unroll
    for (int off = 32; off > 0; off >>= 1) ss += __shfl_down(ss, off, 64);
    __shared__ float part[4];
    if ((tid & 63) == 0) part[tid >> 6] = ss;
    __syncthreads();
    if (tid == 0) {
        float t = part[0] + part[1] + part[2] + part[3];
        invN[row] = 1.0f / (sqrtf(t) + EPSF);
    }
}

// Gram: grid (c=64, kq=8); atomicAdd into zeroed G.
__global__ __launch_bounds__(256) void gram_kernel(
        const float* __restrict__ caps, float* __restrict__ G) {
    int c = blockIdx.x, kq = blockIdx.y;
    const float* cap = caps + (size_t)c * WW * DD + kq * 128;
    __shared__ __align__(16) float cs[64][68];
    int tid = threadIdx.x;
    int tr = tid & 15, tw = tid >> 4;
    float acc[4][4];
    #pragma unroll
    for (int a = 0; a < 4; a++)
        #pragma unroll
        for (int b = 0; b < 4; b++) acc[a][b] = 0.f;

    for (int d0 = 0; d0 < 128; d0 += 64) {
        __syncthreads();
        for (int t = tid; t < 64 * 16; t += 256) {
            int rw = t >> 4, c4 = t & 15;
            float4 v = make_float4(0.f, 0.f, 0.f, 0.f);
            if (rw < WW) v = *(const float4*)(cap + (size_t)rw * DD + d0 + c4 * 4);
            *(float4*)&cs[rw][c4 * 4] = v;
        }
        __syncthreads();
        #pragma unroll 4
        for (int k4 = 0; k4 < 16; k4++) {
            float4 a0 = *(const float4*)&cs[tr][k4 * 4];
            float4 a1 = *(const float4*)&cs[tr + 16][k4 * 4];
            float4 a2 = *(const float4*)&cs[tr + 32][k4 * 4];
            float4 a3 = *(const float4*)&cs[tr + 48][k4 * 4];
            float4 b0 = *(const float4*)&cs[tw][k4 * 4];
            float4 b1 = *(const float4*)&cs[tw + 16][k4 * 4];
            float4 b2 = *(const float4*)&cs[tw + 32][k4 * 4];
            float4 b3 = *(const float4*)&cs[tw + 48][k4 * 4];
            fma4(acc[0][0], a0, b0); fma4(acc[0][1], a0, b1);
            fma4(acc[0][2], a0, b2); fma4(acc[0][3], a0, b3);
            fma4(acc[1][0], a1, b0); fma4(acc[1][1], a1, b1);
            fma4(acc[1][2], a1, b2); fma4(acc[1][3], a1, b3);
            fma4(acc[2][0], a2, b0); fma4(acc[2][1], a2, b1);
            fma4(acc[2][2], a2, b2); fma4(acc[2][3], a2, b3);
            fma4(acc[3][0], a3, b0); fma4(acc[3][1], a3, b1);
            fma4(acc[3][2], a3, b2); fma4(acc[3][3], a3, b3);
        }
    }
    #pragma unroll
    for (int j = 0; j < 4; j++) {
        int wp = tr + 16 * j;
        if (wp >= WW) continue;
        #pragma unroll
        for (int l = 0; l < 4; l++) {
            int w = tw + 16 * l;
            if (w < WW) atomicAdd(&G[(size_t)c * WW * WW + wp * WW + w], acc[j][l]);
        }
    }
}

// G fp32 -> padded 64x64 bf16 hi/lo per caption
__global__ __launch_bounds__(256) void g2bf_kernel(
        const float* __restrict__ G, unsigned short* __restrict__ Gh,
        unsigned short* __restrict__ Gl) {
    int c = blockIdx.x;
    int tid = threadIdx.x;
    for (int t = tid; t < 4096; t += 256) {
        int w = t >> 6, wp = t & 63;
        float g = (w < WW && wp < WW) ? G[(size_t)c * WW * WW + w * WW + wp] : 0.f;
        unsigned short h = f2bf(g);
        Gh[(size_t)c * 4096 + t] = h;
        Gl[(size_t)c * 4096 + t] = f2bf(g - bf2f(h));
    }
}

// T = A[2304x1024] @ B[3200x1024]^T via 3-pass hi/lo bf16 MFMA.
// Block tile 128x128, BK=32, 4 waves each 64x64.
__global__ __launch_bounds__(256) void gemm_mfma_kernel(
        const unsigned short* __restrict__ Ah, const unsigned short* __restrict__ Al,
        const unsigned short* __restrict__ Bh, const unsigned short* __restrict__ Bl,
        float* __restrict__ T) {
    __shared__ __align__(16) unsigned short sAh[128 * 32], sAl[128 * 32];
    __shared__ __align__(16) unsigned short sBh[128 * 32], sBl[128 * 32];
    int tid = threadIdx.x;
    int lane = tid & 63, wv = tid >> 6;
    int m0 = blockIdx.y * 128, n0 = blockIdx.x * 128;
    int rw = (wv & 1) * 64;
    int cw = (wv >> 1) * 64;

    f32x4 acc[4][4] = {};

    int srow = lane >> 2;
    int scol = (lane & 3) * 8;
    int fm = lane & 15;
    int fk = (lane >> 4) * 8;

    for (int k0 = 0; k0 < GK; k0 += 32) {
        __syncthreads();
        #pragma unroll
        for (int j = 0; j < 2; j++) {
            int seg = wv * 2 + j;
            int row = seg * 16 + srow;
            size_t ga = (size_t)(m0 + row) * GK + k0 + scol;
            size_t gb = (size_t)(n0 + row) * GK + k0 + scol;
            __builtin_amdgcn_global_load_lds(
                (const __attribute__((address_space(1))) void*)(Ah + ga),
                (__attribute__((address_space(3))) void*)(sAh + seg * 512), 16, 0, 0);
            __builtin_amdgcn_global_load_lds(
                (const __attribute__((address_space(1))) void*)(Al + ga),
                (__attribute__((address_space(3))) void*)(sAl + seg * 512), 16, 0, 0);
            __builtin_amdgcn_global_load_lds(
                (const __attribute__((address_space(1))) void*)(Bh + gb),
                (__attribute__((address_space(3))) void*)(sBh + seg * 512), 16, 0, 0);
            __builtin_amdgcn_global_load_lds(
                (const __attribute__((address_space(1))) void*)(Bl + gb),
                (__attribute__((address_space(3))) void*)(sBl + seg * 512), 16, 0, 0);
        }
        __syncthreads();

        bf16x8 fah[4], fal[4], fbh[4], fbl[4];
        #pragma unroll
        for (int t = 0; t < 4; t++) {
            int offa = (rw + t * 16 + fm) * 32 + fk;
            int offb = (cw + t * 16 + fm) * 32 + fk;
            fah[t] = *(const bf16x8*)&sAh[offa];
            fal[t] = *(const bf16x8*)&sAl[offa];
            fbh[t] = *(const bf16x8*)&sBh[offb];
            fbl[t] = *(const bf16x8*)&sBl[offb];
        }
        #pragma unroll
        for (int mt = 0; mt < 4; mt++)
            #pragma unroll
            for (int nt = 0; nt < 4; nt++) {
                acc[mt][nt] = __builtin_amdgcn_mfma_f32_16x16x32_bf16(
                    fah[mt], fbh[nt], acc[mt][nt], 0, 0, 0);
                acc[mt][nt] = __builtin_amdgcn_mfma_f32_16x16x32_bf16(
                    fah[mt], fbl[nt], acc[mt][nt], 0, 0, 0);
                acc[mt][nt] = __builtin_amdgcn_mfma_f32_16x16x32_bf16(
                    fal[mt], fbh[nt], acc[mt][nt], 0, 0, 0);
            }
    }

    int orow0 = m0 + rw + (lane >> 4) * 4;
    int ocol0 = n0 + cw + (lane & 15);
    #pragma unroll
    for (int mt = 0; mt < 4; mt++)
        #pragma unroll
        for (int nt = 0; nt < 4; nt++)
            #pragma unroll
            for (int v = 0; v < 4; v++)
                T[(size_t)(orow0 + mt * 16 + v) * GN + ocol0 + nt * 16] = acc[mt][nt][v];
}

// Epilogue v3: one block per (c, i); grid 64x64 = 4096 blocks.
// Softmax reads T straight from global (no reuse -> no staging). M stored only
// as bf16 hi/lo (MFMA consumes it; den2 reconstructs fp32 = hi+lo).
#define MST 72   // sM row stride in ushorts (144 B, 16B-aligned)
__global__ __launch_bounds__(256) void epi_kernel(
        const float* __restrict__ T,
        const unsigned short* __restrict__ Gh, const unsigned short* __restrict__ Gl,
        const int* __restrict__ img_lens, const int* __restrict__ cap_lens,
        const float* __restrict__ alpha,
        const float* __restrict__ invI, const float* __restrict__ invC,
        float* __restrict__ out) {
    int c = blockIdx.x, i = blockIdx.y;
    __shared__ __align__(16) unsigned short sGh[64 * 64], sGl[64 * 64];
    __shared__ __align__(16) unsigned short sMh[48 * MST], sMl[48 * MST];
    __shared__ __align__(16) float Hsh[36][68];
    __shared__ float numSh[36];
    __shared__ float part[36][4];

    int tid = threadIdx.x;
    int lane = tid & 63, wv = tid >> 6;
    int fm = lane & 15, fk8 = (lane >> 4) * 8;
    int hf = lane >> 5, l5 = lane & 31;

    // stage G (bf16 hi/lo)
    {
        const uint4* gh = (const uint4*)(Gh + (size_t)c * 4096);
        const uint4* gl = (const uint4*)(Gl + (size_t)c * 4096);
        ((uint4*)sGh)[tid] = gh[tid];
        ((uint4*)sGh)[tid + 256] = gh[tid + 256];
        ((uint4*)sGl)[tid] = gl[tid];
        ((uint4*)sGl)[tid + 256] = gl[tid + 256];
    }
    // zero M pad rows 36..47 (A-operand rows for mt=2)
    for (int t = tid; t < 12 * MST; t += 256) {
        sMh[36 * MST + t] = 0; sMl[36 * MST + t] = 0;
    }
    __syncthreads();

    // hoist G fragments: wave wv owns col-tile wv
    bf16x8 gfh[2], gfl[2];
    #pragma unroll
    for (int ks = 0; ks < 2; ks++) {
        int off = (wv * 16 + fm) * 64 + ks * 32 + fk8;
        gfh[ks] = *(const bf16x8*)&sGh[off];
        gfl[ks] = *(const bf16x8*)&sGl[off];
    }

    int lc = cap_lens[c], li = img_lens[i];
    float a_mix = 1.0f / (1.0f + __expf(-alpha[0]));
    float oma = 1.0f - a_mix;
    float invC0 = invC[c * WW + l5];
    float invC1 = (l5 + 32 < WW) ? invC[c * WW + l5 + 32] : 0.f;
    bool v0 = l5 < lc, v1 = (l5 + 32) < lc;

    // softmax/argmax/mix: half-wave per row, T from global (L2-hot)
    for (int r = wv * 2 + hf; r < RR; r += 8) {
        float inv_ir = invI[i * RR + r];
        const float* Trow = T + (size_t)(i * RR + r) * GN + c * WW;
        float T0 = Trow[l5];
        float T1 = (l5 + 32 < WW) ? Trow[l5 + 32] : 0.f;
        float S0 = v0 ? (T0 * inv_ir * invC0) : -2.f;
        float S1 = v1 ? (T1 * inv_ir * invC1) : -2.f;
        float mv; int mi;
        if (S1 > S0) { mv = S1; mi = l5 + 32; } else { mv = S0; mi = l5; }
        #pragma unroll
        for (int m = 1; m < 32; m <<= 1) {
            float ov = __shfl_xor(mv, m, 32);
            int oi = __shfl_xor(mi, m, 32);
            if (ov > mv || (ov == mv && oi < mi)) { mv = ov; mi = oi; }
        }
        float e0 = v0 ? __expf((S0 - mv) * 10.f) : 0.f;
        float e1 = v1 ? __expf((S1 - mv) * 10.f) : 0.f;
        float ss = e0 + e1, nm = fmaf(e0, T0, e1 * T1);
        #pragma unroll
        for (int m = 1; m < 32; m <<= 1) {
            ss += __shfl_xor(ss, m, 32);
            nm += __shfl_xor(nm, m, 32);
        }
        float Tmi = (mi < 32) ? __shfl(T0, mi, 32) : __shfl(T1, mi - 32, 32);
        float scale = a_mix / ss;
        float m0 = e0 * scale + (l5 == mi ? oma : 0.f);
        float m1 = e1 * scale + (l5 + 32 == mi ? oma : 0.f);
        if (l5 == 0) numSh[r] = fmaf(nm, scale, oma * Tmi);
        unsigned short h0 = f2bf(m0), h1 = f2bf(m1);
        sMh[r * MST + l5] = h0;
        sMl[r * MST + l5] = f2bf(m0 - bf2f(h0));
        sMh[r * MST + l5 + 32] = h1;
        sMl[r * MST + l5 + 32] = f2bf(m1 - bf2f(h1));
    }
    __syncthreads();

    // H = M * G via MFMA (3-pass hi/lo); wave wv owns col-tile wv
    int quad4 = (lane >> 4) * 4;
    #pragma unroll
    for (int mt = 0; mt < 3; mt++) {
        f32x4 acc = {0.f, 0.f, 0.f, 0.f};
        #pragma unroll
        for (int ks = 0; ks < 2; ks++) {
            int off = (mt * 16 + fm) * MST + ks * 32 + fk8;
            bf16x8 mh = *(const bf16x8*)&sMh[off];
            bf16x8 ml = *(const bf16x8*)&sMl[off];
            acc = __builtin_amdgcn_mfma_f32_16x16x32_bf16(mh, gfh[ks], acc, 0, 0, 0);
            acc = __builtin_amdgcn_mfma_f32_16x16x32_bf16(mh, gfl[ks], acc, 0, 0, 0);
            acc = __builtin_amdgcn_mfma_f32_16x16x32_bf16(ml, gfh[ks], acc, 0, 0, 0);
        }
        #pragma unroll
        for (int v = 0; v < 4; v++) {
            int row = mt * 16 + quad4 + v;
            if (row < RR) Hsh[row][wv * 16 + fm] = acc[v];
        }
    }
    __syncthreads();

    // den2 = rowsum(M .* H), M reconstructed from hi/lo
    if (tid < 144) {
        int r = tid >> 2, j = tid & 3;
        const bf16x8* mh = (const bf16x8*)&sMh[r * MST + j * 16];
        const bf16x8* ml = (const bf16x8*)&sMl[r * MST + j * 16];
        float p = 0.f;
        #pragma unroll
        for (int g = 0; g < 2; g++) {
            bf16x8 h8 = mh[g], l8 = ml[g];
            #pragma unroll
            for (int q = 0; q < 8; q++) {
                float m = bf2f((unsigned short)h8[q]) + bf2f((unsigned short)l8[q]);
                p = fmaf(m, Hsh[r][j * 16 + g * 8 + q], p);
            }
        }
        part[r][j] = p;
    }
    __syncthreads();
    if (tid < RR) {
        float den2 = part[tid][0] + part[tid][1] + part[tid][2] + part[tid][3];
        float res = (tid < li) ? (numSh[tid] / (sqrtf(den2) + EPSF)) : -1.0f;
        out[((size_t)i * BB + c) * RR + tid] = res;
    }
}

extern "C" void kernel_launch(void* const* d_in, const int* in_sizes, int n_in,
                              void* d_out, int out_size, void* d_ws, size_t ws_size,
                              hipStream_t stream) {
    const float* imgs = (const float*)d_in[0];
    const float* caps = (const float*)d_in[1];
    const int* img_lens = (const int*)d_in[2];
    const int* cap_lens = (const int*)d_in[3];
    const float* alpha = (const float*)d_in[4];
    float* out = (float*)d_out;

    float* ws = (float*)d_ws;
    float* invI = ws;                              // 2304
    float* invC = ws + BB * RR;                    // 3200
    float* G = ws + BB * RR + BB * WW;             // 160000
    float* T = G + BB * WW * WW;                   // 7372800
    unsigned short* Ah = (unsigned short*)(T + (size_t)GM * GN);
    unsigned short* Al = Ah + (size_t)GM * GK;
    unsigned short* Bh = Al + (size_t)GM * GK;
    unsigned short* Bl = Bh + (size_t)GN * GK;
    unsigned short* Gbh = Bl + (size_t)GN * GK;    // 64*4096
    unsigned short* Gbl = Gbh + (size_t)BB * 4096;

    hipMemsetAsync(G, 0, (size_t)BB * WW * WW * sizeof(float), stream);
    convert_norm_kernel<<<GM, 256, 0, stream>>>(imgs, Ah, Al, invI);
    convert_norm_kernel<<<GN, 256, 0, stream>>>(caps, Bh, Bl, invC);
    gram_kernel<<<dim3(BB, 8), 256, 0, stream>>>(caps, G);
    g2bf_kernel<<<BB, 256, 0, stream>>>(G, Gbh, Gbl);
    gemm_mfma_kernel<<<dim3(GN / 128, GM / 128), 256, 0, stream>>>(Ah, Al, Bh, Bl, T);
    epi_kernel<<<dim3(BB, BB), 256, 0, stream>>>(
        T, Gbh, Gbl, img_lens, cap_lens, alpha, invI, invC, out);
}